// Round 7
// 530.083 us; speedup vs baseline: 1.0851x; 1.0851x over previous
//
#include <hip/hip_runtime.h>

// SpikingConv2D: tj [16,258,258] f32, kernel [128,1,3,3] f32 (flat 9x128 view),
// D_i [9,128] f32 (row 0 only). out[n*128+f], n=(i*256+j)*16+b, Hv=256.
// ti = min(sum_t x[t]*W[t][f] + (1 - D_i[0][f]), 1.0).
//
// R9 = resubmit (six infra failures: container death, then 5x broker
// capacity timeouts — this design has never run on device).
// One WAVE = one task (batch b, pixel strip j0..j0+3, all 128 filters;
// 2 filters/lane as float2). The 3x6 input patch (18 floats) is wave-uniform
// -> scalar-path loads (no 32x broadcast redundancy of the R2 kernel).
// Patch for task k+1 is double-buffer prefetched (xa/xb) before computing
// task k, hiding L3 latency (~600cy) under FMA issue x 6 waves/SIMD.
// Write side: 512MB nontemporal, 512B contiguous per wave-store; ~85us floor.

#define B_N   16
#define S_N   258
#define HV_N  256
#define F_N   128

#define GRID      8192
#define WPB       4                             // waves per block
#define NSTREAM   (GRID * WPB)                  // 32768 waves in flight
#define NTASK     ((HV_N * (HV_N / 4)) * B_N)   // 262144 wave-tasks

typedef float v2f __attribute__((ext_vector_type(2)));

__global__ __launch_bounds__(256, 6) void spiking_conv2d_kernel(
    const float* __restrict__ tj, const float* __restrict__ kern,
    const float* __restrict__ Di, float* __restrict__ out) {
  const int lane = threadIdx.x & 63;
  const int wid  = __builtin_amdgcn_readfirstlane(threadIdx.x >> 6);

  // W[t][f], f = 2*lane, 2*lane+1. Registers, loaded once (per-lane vector ld).
  float2 w[9];
#pragma unroll
  for (int t = 0; t < 9; ++t)
    w[t] = reinterpret_cast<const float2*>(kern)[t * (F_N / 2) + lane];
  const float2 d = reinterpret_cast<const float2*>(Di)[lane];
  const float thx = 1.0f - d.x, thy = 1.0f - d.y;

  // task t: b = t&15, pblk = t>>4, j0 = (pblk&63)*4, i = pblk>>6
  auto load_task = [&](int t, float (&x)[18]) {
    const int b    = t & (B_N - 1);
    const int pblk = t >> 4;
    const int j0   = (pblk & 63) << 2;
    const int i    = pblk >> 6;
    const float* s = tj + (b * S_N + i) * S_N + j0;  // wave-uniform address
#pragma unroll
    for (int r = 0; r < 3; ++r)
#pragma unroll
      for (int c = 0; c < 6; ++c)
        x[r * 6 + c] = s[r * S_N + c];
  };

  auto compute_store = [&](int t, const float (&x)[18]) {
    const int b    = t & (B_N - 1);
    const int pblk = t >> 4;
    const int j0   = (pblk & 63) << 2;
    const int i    = pblk >> 6;
    const int n0   = ((i * HV_N + j0) << 4) | b;  // row id, < 2^20
    v2f* o = reinterpret_cast<v2f*>(out) + (long)n0 * (F_N / 2) + lane;
#pragma unroll
    for (int p = 0; p < 4; ++p) {
      float ax = thx, ay = thy;
#pragma unroll
      for (int r = 0; r < 3; ++r)
#pragma unroll
        for (int c = 0; c < 3; ++c) {         // tap order == R2 kernel:
          const float xv = x[r * 6 + p + c];  // bitwise-identical results
          ax = fmaf(xv, w[r * 3 + c].x, ax);
          ay = fmaf(xv, w[r * 3 + c].y, ay);
        }
      v2f v = {fminf(ax, 1.0f), fminf(ay, 1.0f)};
      // pixel p -> row n0 + 16p -> +p*1024 float2; wave writes 512B contiguous
      __builtin_nontemporal_store(v, o + p * (16 * (F_N / 2)));
    }
  };

  float xa[18], xb[18];
  int t = blockIdx.x * WPB + wid;
  if (t >= NTASK) return;  // defensive; exact with GRID=8192
  load_task(t, xa);
#pragma unroll 1
  for (; t + NSTREAM < NTASK; ) {
    load_task(t + NSTREAM, xb);     // prefetch next while computing current
    compute_store(t, xa);
    t += NSTREAM;
    if (t + NSTREAM < NTASK) {
      load_task(t + NSTREAM, xa);   // prefetch next-next
      compute_store(t, xb);
      t += NSTREAM;
    } else {
      compute_store(t, xb);
      t += NSTREAM;  // terminates loop
    }
  }
  if (t < NTASK) compute_store(t, xa);  // tail (not hit with exact config)
}

extern "C" void kernel_launch(void* const* d_in, const int* in_sizes, int n_in,
                              void* d_out, int out_size, void* d_ws, size_t ws_size,
                              hipStream_t stream) {
  const float* tj   = (const float*)d_in[0];
  const float* kern = (const float*)d_in[1];
  const float* Di   = (const float*)d_in[2];
  float* out = (float*)d_out;
  spiking_conv2d_kernel<<<GRID, 256, 0, stream>>>(tj, kern, Di, out);
}